// Round 1
// baseline (1189.448 us; speedup 1.0000x reference)
//
#include <hip/hip_runtime.h>

typedef unsigned short u16;
typedef unsigned int   u32;
typedef __bf16 bf16_t;
typedef bf16_t bf16x8 __attribute__((ext_vector_type(8)));
typedef float  f32x4  __attribute__((ext_vector_type(4)));

// ---------- fp32 <-> bf16 helpers (RNE) ----------
__device__ __forceinline__ u16 f2bf(float f) {
  u32 u = __builtin_bit_cast(u32, f);
  u32 r = u + 0x7fffu + ((u >> 16) & 1u);
  return (u16)(r >> 16);
}
__device__ __forceinline__ float bf2f(u16 h) {
  u32 u = ((u32)h) << 16;
  return __builtin_bit_cast(float, u);
}

// ---------- elementwise fp32 -> bf16 convert (4 el/thread) ----------
__global__ __launch_bounds__(256) void k_cvt(const float* __restrict__ in,
                                             u16* __restrict__ out, long n4) {
  long i = (long)blockIdx.x * 256 + threadIdx.x;
  if (i >= n4) return;
  float4 v = reinterpret_cast<const float4*>(in)[i];
  ushort4 o;
  o.x = f2bf(v.x); o.y = f2bf(v.y); o.z = f2bf(v.z); o.w = f2bf(v.w);
  reinterpret_cast<ushort4*>(out)[i] = o;
}

// ---------- W[K][N] fp32 -> Wt[N][K] bf16 (32x32 tiles) ----------
__global__ __launch_bounds__(256) void k_transpose_cvt(const float* __restrict__ W,
                                                       u16* __restrict__ Wt,
                                                       int K, int N) {
  __shared__ u16 tile[32][33];
  int n0 = blockIdx.x * 32, k0 = blockIdx.y * 32;
  int tx = threadIdx.x & 31, ty = threadIdx.x >> 5;
#pragma unroll
  for (int i = 0; i < 4; ++i) {
    int k = ty + i * 8;
    tile[k][tx] = f2bf(W[(size_t)(k0 + k) * N + n0 + tx]);
  }
  __syncthreads();
#pragma unroll
  for (int i = 0; i < 4; ++i) {
    int n = ty + i * 8;
    Wt[(size_t)(n0 + n) * K + k0 + tx] = tile[tx][n];
  }
}

// ---------- GEMM: C[M,N] = A[M,K] @ Bt[N,K]^T + bias, optional ReLU ----------
// 256 thr = 4 waves (2x2), tile 128x128, BK=64, pad-72 LDS (2-way-per-phase reads/writes).
template<int RELU>
__global__ __launch_bounds__(256) void k_gemm_bt(
    const u16* __restrict__ A, const u16* __restrict__ Bt,
    const float* __restrict__ bias, u16* __restrict__ C,
    int M, int N, int K)
{
  __shared__ u16 As[128][72];
  __shared__ u16 Bs[128][72];
  const int tid = threadIdx.x;
  const int lane = tid & 63, wid = tid >> 6;
  const int wr = wid >> 1, wc = wid & 1;
  const int l15 = lane & 15, g = lane >> 4;
  const int bm = blockIdx.x * 128, bn = blockIdx.y * 128;

  f32x4 acc[4][4] = {};

  for (int kt = 0; kt < K; kt += 64) {
#pragma unroll
    for (int i = 0; i < 4; ++i) {
      int c = i * 256 + tid;
      int row = c >> 3, kc = (c & 7) * 8;
      *reinterpret_cast<uint4*>(&As[row][kc]) =
          *reinterpret_cast<const uint4*>(A + (size_t)(bm + row) * K + kt + kc);
      *reinterpret_cast<uint4*>(&Bs[row][kc]) =
          *reinterpret_cast<const uint4*>(Bt + (size_t)(bn + row) * K + kt + kc);
    }
    __syncthreads();
#pragma unroll
    for (int ks = 0; ks < 2; ++ks) {
      bf16x8 af[4], bfr[4];
#pragma unroll
      for (int m = 0; m < 4; ++m)
        af[m] = *reinterpret_cast<const bf16x8*>(&As[wr * 64 + m * 16 + l15][ks * 32 + g * 8]);
#pragma unroll
      for (int n = 0; n < 4; ++n)
        bfr[n] = *reinterpret_cast<const bf16x8*>(&Bs[wc * 64 + n * 16 + l15][ks * 32 + g * 8]);
#pragma unroll
      for (int m = 0; m < 4; ++m)
#pragma unroll
        for (int n = 0; n < 4; ++n)
          acc[m][n] = __builtin_amdgcn_mfma_f32_16x16x32_bf16(af[m], bfr[n], acc[m][n], 0, 0, 0);
    }
    __syncthreads();
  }
#pragma unroll
  for (int n = 0; n < 4; ++n) {
    int col = bn + wc * 64 + n * 16 + l15;
    float bv = bias[col];
#pragma unroll
    for (int m = 0; m < 4; ++m) {
      int row0 = bm + wr * 64 + m * 16 + g * 4;
#pragma unroll
      for (int r = 0; r < 4; ++r) {
        float v = acc[m][n][r] + bv;
        if (RELU) v = fmaxf(v, 0.f);
        C[(size_t)(row0 + r) * N + col] = f2bf(v);
      }
    }
  }
}

// ---------- flash attention: O = softmax(Q K^T / 8) V, hd=64 ----------
// Block = 256 thr (4 waves); each wave owns 16 q-rows; 32-key tiles; online softmax.
__global__ __launch_bounds__(256) void k_flash(
    const u16* __restrict__ Qg, const u16* __restrict__ Kg, const u16* __restrict__ Vg,
    u16* __restrict__ Og,
    long long qbs, int qhs, int qrs,
    long long kbs, int khs, int krs,
    long long obs, int ohs, int ors,
    int Tk)
{
  __shared__ u16 Ks[32][72];
  __shared__ u16 Vt[64][40];     // Vt[hd][key]
  __shared__ u16 Ps[4][16][40];  // per-wave P tile [qrow][key]
  const int tid = threadIdx.x;
  const int lane = tid & 63, wid = tid >> 6;
  const int l15 = lane & 15, g = lane >> 4;
  const int b = blockIdx.y >> 4, h = blockIdx.y & 15;

  const u16* Q  = Qg + (size_t)b * qbs + (size_t)h * qhs;
  const u16* Kp = Kg + (size_t)b * kbs + (size_t)h * khs;
  const u16* Vq = Vg + (size_t)b * kbs + (size_t)h * khs;
  u16* Op = Og + (size_t)b * obs + (size_t)h * ohs;

  const int q0 = blockIdx.x * 64 + wid * 16;

  bf16x8 qf[2];
#pragma unroll
  for (int ks2 = 0; ks2 < 2; ++ks2)
    qf[ks2] = *reinterpret_cast<const bf16x8*>(Q + (size_t)(q0 + l15) * qrs + ks2 * 32 + g * 8);

  f32x4 oacc[4] = {};
  float mrow[4], lrow[4];
#pragma unroll
  for (int r = 0; r < 4; ++r) { mrow[r] = -1e30f; lrow[r] = 0.f; }

  for (int kt = 0; kt < Tk; kt += 32) {
    { // stage K tile 32x64 (one uint4 per thread)
      int row = tid >> 3, kc = (tid & 7) * 8;
      *reinterpret_cast<uint4*>(&Ks[row][kc]) =
          *reinterpret_cast<const uint4*>(Kp + (size_t)(kt + row) * krs + kc);
    }
#pragma unroll
    for (int i = 0; i < 8; ++i) { // stage V transposed: Vt[hd][key]
      int key = i * 4 + wid;
      Vt[lane][key] = Vq[(size_t)(kt + key) * krs + lane];
    }
    __syncthreads();

    // QK^T -> scores 16x32 (2 key-blocks)
    f32x4 sc[2] = {};
#pragma unroll
    for (int ks2 = 0; ks2 < 2; ++ks2) {
#pragma unroll
      for (int nb = 0; nb < 2; ++nb) {
        bf16x8 kf = *reinterpret_cast<const bf16x8*>(&Ks[nb * 16 + l15][ks2 * 32 + g * 8]);
        sc[nb] = __builtin_amdgcn_mfma_f32_16x16x32_bf16(qf[ks2], kf, sc[nb], 0, 0, 0);
      }
    }
    // online softmax update (rows = g*4+r, 16 lanes per row share stats)
#pragma unroll
    for (int r = 0; r < 4; ++r) {
      float s0 = sc[0][r] * 0.125f, s1 = sc[1][r] * 0.125f;
      float tm = fmaxf(s0, s1);
      tm = fmaxf(tm, __shfl_xor(tm, 1));
      tm = fmaxf(tm, __shfl_xor(tm, 2));
      tm = fmaxf(tm, __shfl_xor(tm, 4));
      tm = fmaxf(tm, __shfl_xor(tm, 8));
      float mnew = fmaxf(mrow[r], tm);
      float scl = __expf(mrow[r] - mnew);
      float e0 = __expf(s0 - mnew), e1 = __expf(s1 - mnew);
      float ps = e0 + e1;
      ps += __shfl_xor(ps, 1);
      ps += __shfl_xor(ps, 2);
      ps += __shfl_xor(ps, 4);
      ps += __shfl_xor(ps, 8);
      lrow[r] = lrow[r] * scl + ps;
      mrow[r] = mnew;
#pragma unroll
      for (int nb = 0; nb < 4; ++nb) oacc[nb][r] *= scl;
      Ps[wid][g * 4 + r][l15]      = f2bf(e0);
      Ps[wid][g * 4 + r][16 + l15] = f2bf(e1);
    }
    asm volatile("s_waitcnt lgkmcnt(0)" ::: "memory");
    // PV
    bf16x8 pf = *reinterpret_cast<const bf16x8*>(&Ps[wid][l15][g * 8]);
#pragma unroll
    for (int nb = 0; nb < 4; ++nb) {
      bf16x8 vf = *reinterpret_cast<const bf16x8*>(&Vt[nb * 16 + l15][g * 8]);
      oacc[nb] = __builtin_amdgcn_mfma_f32_16x16x32_bf16(pf, vf, oacc[nb], 0, 0, 0);
    }
    __syncthreads();
  }
#pragma unroll
  for (int nb = 0; nb < 4; ++nb)
#pragma unroll
    for (int r = 0; r < 4; ++r) {
      float v = oacc[nb][r] / lrow[r];
      Op[(size_t)(q0 + g * 4 + r) * ors + nb * 16 + l15] = f2bf(v);
    }
}

// ---------- fused add + LayerNorm over D=1024 (one row per block) ----------
__device__ __forceinline__ void load4v(const float* p, float* v) {
  float4 t = *reinterpret_cast<const float4*>(p);
  v[0] = t.x; v[1] = t.y; v[2] = t.z; v[3] = t.w;
}
__device__ __forceinline__ void load4v(const u16* p, float* v) {
  ushort4 t = *reinterpret_cast<const ushort4*>(p);
  v[0] = bf2f(t.x); v[1] = bf2f(t.y); v[2] = bf2f(t.z); v[3] = bf2f(t.w);
}
__device__ __forceinline__ void store4v(float* p, const float* v) {
  float4 t; t.x = v[0]; t.y = v[1]; t.z = v[2]; t.w = v[3];
  *reinterpret_cast<float4*>(p) = t;
}
__device__ __forceinline__ void store4v(u16* p, const float* v) {
  ushort4 t; t.x = f2bf(v[0]); t.y = f2bf(v[1]); t.z = f2bf(v[2]); t.w = f2bf(v[3]);
  *reinterpret_cast<ushort4*>(p) = t;
}

template<typename TRES, typename TOUT>
__global__ __launch_bounds__(256) void k_add_ln(
    const u16* __restrict__ X, const TRES* __restrict__ R,
    const float* __restrict__ gamma, const float* __restrict__ beta,
    TOUT* __restrict__ Out)
{
  const int row = blockIdx.x;
  const int tid = threadIdx.x;
  const size_t base = (size_t)row * 1024 + tid * 4;
  float x[4], rr[4];
  load4v(X + base, x);
  load4v(R + base, rr);
  float v[4];
#pragma unroll
  for (int j = 0; j < 4; ++j) v[j] = x[j] + rr[j];
  float s = v[0] + v[1] + v[2] + v[3];
  float q = v[0]*v[0] + v[1]*v[1] + v[2]*v[2] + v[3]*v[3];
#pragma unroll
  for (int off = 32; off > 0; off >>= 1) {
    s += __shfl_down(s, off);
    q += __shfl_down(q, off);
  }
  __shared__ float sh[8];
  const int lane = tid & 63, wid = tid >> 6;
  if (lane == 0) { sh[wid] = s; sh[4 + wid] = q; }
  __syncthreads();
  s = sh[0] + sh[1] + sh[2] + sh[3];
  q = sh[4] + sh[5] + sh[6] + sh[7];
  float mean = s * (1.f / 1024.f);
  float var = q * (1.f / 1024.f) - mean * mean;
  float inv = 1.f / sqrtf(var + 1e-5f);
  float gv[4], bv[4], o[4];
  load4v(gamma + tid * 4, gv);
  load4v(beta + tid * 4, bv);
#pragma unroll
  for (int j = 0; j < 4; ++j) o[j] = gv[j] * (v[j] - mean) * inv + bv[j];
  store4v(Out + base, o);
}

// ---------- driver ----------
extern "C" void kernel_launch(void* const* d_in, const int* in_sizes, int n_in,
                              void* d_out, int out_size, void* d_ws, size_t ws_size,
                              hipStream_t stream)
{
  (void)in_sizes; (void)n_in; (void)out_size; (void)ws_size;
  const float* x_enc  = (const float*)d_in[0];
  const float* x_dec  = (const float*)d_in[1];
  const float* qkv_w  = (const float*)d_in[2];
  const float* qkv_b  = (const float*)d_in[3];
  const float* sa_o_w = (const float*)d_in[4];
  const float* sa_o_b = (const float*)d_in[5];
  const float* g1     = (const float*)d_in[6];
  const float* be1    = (const float*)d_in[7];
  const float* q_w    = (const float*)d_in[8];
  const float* q_b    = (const float*)d_in[9];
  const float* kv_w   = (const float*)d_in[10];
  const float* kv_b   = (const float*)d_in[11];
  const float* ca_o_w = (const float*)d_in[12];
  const float* ca_o_b = (const float*)d_in[13];
  const float* g2     = (const float*)d_in[14];
  const float* be2    = (const float*)d_in[15];
  const float* ff_w1  = (const float*)d_in[16];
  const float* ff_b1  = (const float*)d_in[17];
  const float* ff_w2  = (const float*)d_in[18];
  const float* ff_b2  = (const float*)d_in[19];
  const float* g3     = (const float*)d_in[20];
  const float* be3    = (const float*)d_in[21];
  float* out = (float*)d_out;

  u16* Wb = (u16*)d_ws;
  // bf16-element offsets into workspace (~240 MB total)
  const size_t O_WQKV = 0;
  const size_t O_WSAO = O_WQKV + (size_t)3072 * 1024;
  const size_t O_WQ   = O_WSAO + (size_t)1024 * 1024;
  const size_t O_WKV  = O_WQ   + (size_t)1024 * 1024;
  const size_t O_WCAO = O_WKV  + (size_t)2048 * 1024;
  const size_t O_WFF1 = O_WCAO + (size_t)1024 * 1024;
  const size_t O_WFF2 = O_WFF1 + (size_t)4096 * 1024;
  const size_t O_XD   = O_WFF2 + (size_t)1024 * 4096;
  const size_t O_XE   = O_XD + 8388608;
  const size_t O_QKV  = O_XE + 8388608;              // later reused: KV_enc (+QC)
  const size_t O_QC   = O_QKV + 16777216;
  const size_t O_ATT  = O_QKV + 25165824;
  const size_t O_RES  = O_ATT + 8388608;
  const size_t O_RES2 = O_RES + 8388608;
  const size_t O_FF1  = O_RES2 + 8388608;
  const size_t O_GO   = O_FF1 + 33554432;

  // converts
  k_cvt<<<8192, 256, 0, stream>>>(x_dec, Wb + O_XD, 2097152);
  k_cvt<<<8192, 256, 0, stream>>>(x_enc, Wb + O_XE, 2097152);
  // weight transposes (W[K][N] -> Wt[N][K] bf16)
  k_transpose_cvt<<<dim3(96, 32),  256, 0, stream>>>(qkv_w,  Wb + O_WQKV, 1024, 3072);
  k_transpose_cvt<<<dim3(32, 32),  256, 0, stream>>>(sa_o_w, Wb + O_WSAO, 1024, 1024);
  k_transpose_cvt<<<dim3(32, 32),  256, 0, stream>>>(q_w,    Wb + O_WQ,   1024, 1024);
  k_transpose_cvt<<<dim3(64, 32),  256, 0, stream>>>(kv_w,   Wb + O_WKV,  1024, 2048);
  k_transpose_cvt<<<dim3(32, 32),  256, 0, stream>>>(ca_o_w, Wb + O_WCAO, 1024, 1024);
  k_transpose_cvt<<<dim3(128, 32), 256, 0, stream>>>(ff_w1,  Wb + O_WFF1, 1024, 4096);
  k_transpose_cvt<<<dim3(32, 128), 256, 0, stream>>>(ff_w2,  Wb + O_WFF2, 4096, 1024);

  // self-attention branch
  k_gemm_bt<0><<<dim3(64, 24), 256, 0, stream>>>(Wb + O_XD, Wb + O_WQKV, qkv_b,
                                                 Wb + O_QKV, 8192, 3072, 1024);
  k_flash<<<dim3(32, 64), 256, 0, stream>>>(Wb + O_QKV, Wb + O_QKV + 64, Wb + O_QKV + 128,
                                            Wb + O_ATT,
                                            (long long)2048 * 3072, 192, 3072,
                                            (long long)2048 * 3072, 192, 3072,
                                            (long long)2048 * 1024, 64, 1024, 2048);
  k_gemm_bt<0><<<dim3(64, 8), 256, 0, stream>>>(Wb + O_ATT, Wb + O_WSAO, sa_o_b,
                                                Wb + O_GO, 8192, 1024, 1024);
  k_add_ln<float, u16><<<8192, 256, 0, stream>>>(Wb + O_GO, x_dec, g1, be1, Wb + O_RES);

  // cross-attention branch
  k_gemm_bt<0><<<dim3(64, 16), 256, 0, stream>>>(Wb + O_XE, Wb + O_WKV, kv_b,
                                                 Wb + O_QKV, 8192, 2048, 1024);
  k_gemm_bt<0><<<dim3(64, 8), 256, 0, stream>>>(Wb + O_RES, Wb + O_WQ, q_b,
                                                Wb + O_QC, 8192, 1024, 1024);
  k_flash<<<dim3(32, 64), 256, 0, stream>>>(Wb + O_QC, Wb + O_QKV, Wb + O_QKV + 64,
                                            Wb + O_ATT,
                                            (long long)2048 * 1024, 64, 1024,
                                            (long long)2048 * 2048, 128, 2048,
                                            (long long)2048 * 1024, 64, 1024, 2048);
  k_gemm_bt<0><<<dim3(64, 8), 256, 0, stream>>>(Wb + O_ATT, Wb + O_WCAO, ca_o_b,
                                                Wb + O_GO, 8192, 1024, 1024);
  k_add_ln<u16, u16><<<8192, 256, 0, stream>>>(Wb + O_GO, Wb + O_RES, g2, be2, Wb + O_RES2);

  // feed-forward
  k_gemm_bt<1><<<dim3(64, 32), 256, 0, stream>>>(Wb + O_RES2, Wb + O_WFF1, ff_b1,
                                                 Wb + O_FF1, 8192, 4096, 1024);
  k_gemm_bt<0><<<dim3(64, 8), 256, 0, stream>>>(Wb + O_FF1, Wb + O_WFF2, ff_b2,
                                                Wb + O_GO, 8192, 1024, 4096);
  k_add_ln<u16, float><<<8192, 256, 0, stream>>>(Wb + O_GO, Wb + O_RES2, g3, be3, out);
}

// Round 2
// 817.962 us; speedup vs baseline: 1.4542x; 1.4542x over previous
//
#include <hip/hip_runtime.h>

typedef unsigned short u16;
typedef unsigned int   u32;
typedef __bf16 bf16_t;
typedef bf16_t bf16x4 __attribute__((ext_vector_type(4)));
typedef bf16_t bf16x8 __attribute__((ext_vector_type(8)));
typedef float  f32x4  __attribute__((ext_vector_type(4)));

// ---------- fp32 <-> bf16 helpers (RNE) ----------
__device__ __forceinline__ u16 f2bf(float f) {
  u32 u = __builtin_bit_cast(u32, f);
  u32 r = u + 0x7fffu + ((u >> 16) & 1u);
  return (u16)(r >> 16);
}
__device__ __forceinline__ float bf2f(u16 h) {
  u32 u = ((u32)h) << 16;
  return __builtin_bit_cast(float, u);
}

// ---------- elementwise fp32 -> bf16 convert (4 el/thread) ----------
__global__ __launch_bounds__(256) void k_cvt(const float* __restrict__ in,
                                             u16* __restrict__ out, long n4) {
  long i = (long)blockIdx.x * 256 + threadIdx.x;
  if (i >= n4) return;
  float4 v = reinterpret_cast<const float4*>(in)[i];
  ushort4 o;
  o.x = f2bf(v.x); o.y = f2bf(v.y); o.z = f2bf(v.z); o.w = f2bf(v.w);
  reinterpret_cast<ushort4*>(out)[i] = o;
}

// ---------- W[K][N] fp32 -> Wt[N][K] bf16 (32x32 tiles) ----------
__global__ __launch_bounds__(256) void k_transpose_cvt(const float* __restrict__ W,
                                                       u16* __restrict__ Wt,
                                                       int K, int N) {
  __shared__ u16 tile[32][33];
  int n0 = blockIdx.x * 32, k0 = blockIdx.y * 32;
  int tx = threadIdx.x & 31, ty = threadIdx.x >> 5;
#pragma unroll
  for (int i = 0; i < 4; ++i) {
    int k = ty + i * 8;
    tile[k][tx] = f2bf(W[(size_t)(k0 + k) * N + n0 + tx]);
  }
  __syncthreads();
#pragma unroll
  for (int i = 0; i < 4; ++i) {
    int n = ty + i * 8;
    Wt[(size_t)(n0 + n) * K + k0 + tx] = tile[tx][n];
  }
}

// ---------- bf16 V[key][64] (strided) -> Vt[64][Tk] per head ----------
// grid: (Tk/64, B*H). in element [key][d] at base + key*irs + d (head-resolved).
__global__ __launch_bounds__(256) void k_vtrans(const u16* __restrict__ in,
                                                u16* __restrict__ out,
                                                long long ibs, int ihs, int irs,
                                                int Tk) {
  __shared__ u16 t[64][72];
  const int tid = threadIdx.x;
  const int head = blockIdx.y;
  const int b = head >> 4, h = head & 15;
  const int kt = blockIdx.x * 64;
  const u16* ip = in + (size_t)b * ibs + (size_t)h * ihs;
  u16* op = out + (size_t)head * 64 * Tk;
#pragma unroll
  for (int i = 0; i < 2; ++i) {
    int c = i * 256 + tid;
    int key = c >> 3, d = (c & 7) * 8;
    *reinterpret_cast<uint4*>(&t[key][d]) =
        *reinterpret_cast<const uint4*>(ip + (size_t)(kt + key) * irs + d);
  }
  __syncthreads();
#pragma unroll
  for (int i = 0; i < 2; ++i) {
    int c = i * 256 + tid;
    int d = c >> 3, k8 = (c & 7) * 8;
    ushort4 lo, hi;
    lo.x = t[k8 + 0][d]; lo.y = t[k8 + 1][d]; lo.z = t[k8 + 2][d]; lo.w = t[k8 + 3][d];
    hi.x = t[k8 + 4][d]; hi.y = t[k8 + 5][d]; hi.z = t[k8 + 6][d]; hi.w = t[k8 + 7][d];
    uint4 o;
    o.x = ((u32)lo.y << 16) | lo.x; o.y = ((u32)lo.w << 16) | lo.z;
    o.z = ((u32)hi.y << 16) | hi.x; o.w = ((u32)hi.w << 16) | hi.z;
    *reinterpret_cast<uint4*>(op + (size_t)d * Tk + kt + k8) = o;
  }
}

// ---------- GEMM: C[M,N] = A[M,K] @ Bt[N,K]^T + bias, optional ReLU ----------
template<int RELU>
__global__ __launch_bounds__(256) void k_gemm_bt(
    const u16* __restrict__ A, const u16* __restrict__ Bt,
    const float* __restrict__ bias, u16* __restrict__ C,
    int M, int N, int K)
{
  __shared__ u16 As[128][72];
  __shared__ u16 Bs[128][72];
  const int tid = threadIdx.x;
  const int lane = tid & 63, wid = tid >> 6;
  const int wr = wid >> 1, wc = wid & 1;
  const int l15 = lane & 15, g = lane >> 4;
  const int bm = blockIdx.x * 128, bn = blockIdx.y * 128;

  f32x4 acc[4][4] = {};

  for (int kt = 0; kt < K; kt += 64) {
#pragma unroll
    for (int i = 0; i < 4; ++i) {
      int c = i * 256 + tid;
      int row = c >> 3, kc = (c & 7) * 8;
      *reinterpret_cast<uint4*>(&As[row][kc]) =
          *reinterpret_cast<const uint4*>(A + (size_t)(bm + row) * K + kt + kc);
      *reinterpret_cast<uint4*>(&Bs[row][kc]) =
          *reinterpret_cast<const uint4*>(Bt + (size_t)(bn + row) * K + kt + kc);
    }
    __syncthreads();
#pragma unroll
    for (int ks = 0; ks < 2; ++ks) {
      bf16x8 af[4], bfr[4];
#pragma unroll
      for (int m = 0; m < 4; ++m)
        af[m] = *reinterpret_cast<const bf16x8*>(&As[wr * 64 + m * 16 + l15][ks * 32 + g * 8]);
#pragma unroll
      for (int n = 0; n < 4; ++n)
        bfr[n] = *reinterpret_cast<const bf16x8*>(&Bs[wc * 64 + n * 16 + l15][ks * 32 + g * 8]);
#pragma unroll
      for (int m = 0; m < 4; ++m)
#pragma unroll
        for (int n = 0; n < 4; ++n)
          acc[m][n] = __builtin_amdgcn_mfma_f32_16x16x32_bf16(af[m], bfr[n], acc[m][n], 0, 0, 0);
    }
    __syncthreads();
  }
#pragma unroll
  for (int n = 0; n < 4; ++n) {
    int col = bn + wc * 64 + n * 16 + l15;
    float bv = bias[col];
#pragma unroll
    for (int m = 0; m < 4; ++m) {
      int row0 = bm + wr * 64 + m * 16 + g * 4;
#pragma unroll
      for (int r = 0; r < 4; ++r) {
        float v = acc[m][n][r] + bv;
        if (RELU) v = fmaxf(v, 0.f);
        C[(size_t)(row0 + r) * N + col] = f2bf(v);
      }
    }
  }
}

// ---------- flash attention v2: swapped QK^T, pre-transposed V ----------
// O = softmax(Q K^T / 8) V, hd=64. 4 waves x 16 q-rows, 64-key tiles.
// VT layout: [B*H][64][Tk] contiguous (from k_vtrans).
__global__ __launch_bounds__(256) void k_flash2(
    const u16* __restrict__ Qg, const u16* __restrict__ Kg, const u16* __restrict__ VTg,
    u16* __restrict__ Og,
    long long qbs, int qhs, int qrs,
    long long kbs, int khs, int krs,
    long long obs, int ohs, int ors,
    int Tk)
{
  __shared__ u16 Ks[64][72];
  __shared__ u16 Vs[64][72];     // Vs[d][key]
  __shared__ u16 Ps[4][16][72];  // per-wave P tile [qrow][key]
  const int tid = threadIdx.x;
  const int lane = tid & 63, wid = tid >> 6;
  const int l15 = lane & 15, g = lane >> 4;
  const int head = blockIdx.y;
  const int b = head >> 4, h = head & 15;

  const u16* Q  = Qg + (size_t)b * qbs + (size_t)h * qhs;
  const u16* Kp = Kg + (size_t)b * kbs + (size_t)h * khs;
  const u16* Vp = VTg + (size_t)head * 64 * Tk;
  u16* Op = Og + (size_t)b * obs + (size_t)h * ohs;

  const int q0 = blockIdx.x * 64 + wid * 16;

  bf16x8 qf[2];
#pragma unroll
  for (int ks = 0; ks < 2; ++ks)
    qf[ks] = *reinterpret_cast<const bf16x8*>(Q + (size_t)(q0 + l15) * qrs + ks * 32 + g * 8);

  f32x4 oacc[4] = {};
  float m = -1e30f, l = 0.f;   // stats for q-row l15 (lane-local)

  for (int kt = 0; kt < Tk; kt += 64) {
    // stage K[64][64] and Vt[64][64]: 2 x uint4 per thread each, coalesced
#pragma unroll
    for (int i = 0; i < 2; ++i) {
      int c = i * 256 + tid;
      int row = c >> 3, col = (c & 7) * 8;
      *reinterpret_cast<uint4*>(&Ks[row][col]) =
          *reinterpret_cast<const uint4*>(Kp + (size_t)(kt + row) * krs + col);
      *reinterpret_cast<uint4*>(&Vs[row][col]) =
          *reinterpret_cast<const uint4*>(Vp + (size_t)row * Tk + kt + col);
    }
    __syncthreads();

    // swapped QK^T: sc[kb] = C[key in 16-block][qrow]; lane owns qrow=l15,
    // keys kb*16 + g*4 + r
    f32x4 sc[4] = {};
#pragma unroll
    for (int ks = 0; ks < 2; ++ks) {
#pragma unroll
      for (int kb = 0; kb < 4; ++kb) {
        bf16x8 kf = *reinterpret_cast<const bf16x8*>(&Ks[kb * 16 + l15][ks * 32 + g * 8]);
        sc[kb] = __builtin_amdgcn_mfma_f32_16x16x32_bf16(kf, qf[ks], sc[kb], 0, 0, 0);
      }
    }
    // scale + row max (16 values local, then 2 shuffles across g-groups)
    float pm = -1e30f;
#pragma unroll
    for (int kb = 0; kb < 4; ++kb)
#pragma unroll
      for (int r = 0; r < 4; ++r) {
        sc[kb][r] *= 0.125f;
        pm = fmaxf(pm, sc[kb][r]);
      }
    pm = fmaxf(pm, __shfl_xor(pm, 16));
    pm = fmaxf(pm, __shfl_xor(pm, 32));

    // defer-max (T13): skip rescale when max growth <= 8
    const bool rescale = !__all(pm <= m + 8.f);
    float scl = 1.f;
    if (rescale) {
      float mnew = fmaxf(m, pm);
      scl = __expf(m - mnew);
      m = mnew;
    }
    // exp + sum + pack to bf16 P
    float ls = 0.f;
#pragma unroll
    for (int kb = 0; kb < 4; ++kb) {
      bf16x4 pk;
#pragma unroll
      for (int r = 0; r < 4; ++r) {
        float e = __expf(sc[kb][r] - m);
        ls += e;
        pk[r] = (bf16_t)e;
      }
      *reinterpret_cast<bf16x4*>(&Ps[wid][l15][kb * 16 + g * 4]) = pk;
    }
    ls += __shfl_xor(ls, 16);
    ls += __shfl_xor(ls, 32);
    if (rescale) {
      l = l * scl + ls;
      // broadcast scl of row g*4+r (held at lane 20*g+r) and rescale O
#pragma unroll
      for (int r = 0; r < 4; ++r) {
        float sr = __shfl(scl, 20 * g + r);
#pragma unroll
        for (int nb = 0; nb < 4; ++nb) oacc[nb][r] *= sr;
      }
    } else {
      l += ls;
    }
    asm volatile("s_waitcnt lgkmcnt(0)" ::: "memory");
    // PV: A-frag = P[qrow=l15][key], B-frag = Vt[d=nb*16+l15][key]
#pragma unroll
    for (int kc = 0; kc < 2; ++kc) {
      bf16x8 pf = *reinterpret_cast<const bf16x8*>(&Ps[wid][l15][kc * 32 + g * 8]);
#pragma unroll
      for (int nb = 0; nb < 4; ++nb) {
        bf16x8 vf = *reinterpret_cast<const bf16x8*>(&Vs[nb * 16 + l15][kc * 32 + g * 8]);
        oacc[nb] = __builtin_amdgcn_mfma_f32_16x16x32_bf16(pf, vf, oacc[nb], 0, 0, 0);
      }
    }
    __syncthreads();
  }
  // epilogue: l for row g*4+r lives at lane 20*g+r
#pragma unroll
  for (int r = 0; r < 4; ++r) {
    float lr = __shfl(l, 20 * g + r);
    float inv = 1.f / lr;
#pragma unroll
    for (int nb = 0; nb < 4; ++nb)
      Op[(size_t)(q0 + g * 4 + r) * ors + nb * 16 + l15] = f2bf(oacc[nb][r] * inv);
  }
}

// ---------- fused add + LayerNorm over D=1024 (one row per block) ----------
__device__ __forceinline__ void load4v(const float* p, float* v) {
  float4 t = *reinterpret_cast<const float4*>(p);
  v[0] = t.x; v[1] = t.y; v[2] = t.z; v[3] = t.w;
}
__device__ __forceinline__ void load4v(const u16* p, float* v) {
  ushort4 t = *reinterpret_cast<const ushort4*>(p);
  v[0] = bf2f(t.x); v[1] = bf2f(t.y); v[2] = bf2f(t.z); v[3] = bf2f(t.w);
}
__device__ __forceinline__ void store4v(float* p, const float* v) {
  float4 t; t.x = v[0]; t.y = v[1]; t.z = v[2]; t.w = v[3];
  *reinterpret_cast<float4*>(p) = t;
}
__device__ __forceinline__ void store4v(u16* p, const float* v) {
  ushort4 t; t.x = f2bf(v[0]); t.y = f2bf(v[1]); t.z = f2bf(v[2]); t.w = f2bf(v[3]);
  *reinterpret_cast<ushort4*>(p) = t;
}

template<typename TRES, typename TOUT>
__global__ __launch_bounds__(256) void k_add_ln(
    const u16* __restrict__ X, const TRES* __restrict__ R,
    const float* __restrict__ gamma, const float* __restrict__ beta,
    TOUT* __restrict__ Out)
{
  const int row = blockIdx.x;
  const int tid = threadIdx.x;
  const size_t base = (size_t)row * 1024 + tid * 4;
  float x[4], rr[4];
  load4v(X + base, x);
  load4v(R + base, rr);
  float v[4];
#pragma unroll
  for (int j = 0; j < 4; ++j) v[j] = x[j] + rr[j];
  float s = v[0] + v[1] + v[2] + v[3];
  float q = v[0]*v[0] + v[1]*v[1] + v[2]*v[2] + v[3]*v[3];
#pragma unroll
  for (int off = 32; off > 0; off >>= 1) {
    s += __shfl_down(s, off);
    q += __shfl_down(q, off);
  }
  __shared__ float sh[8];
  const int lane = tid & 63, wid = tid >> 6;
  if (lane == 0) { sh[wid] = s; sh[4 + wid] = q; }
  __syncthreads();
  s = sh[0] + sh[1] + sh[2] + sh[3];
  q = sh[4] + sh[5] + sh[6] + sh[7];
  float mean = s * (1.f / 1024.f);
  float var = q * (1.f / 1024.f) - mean * mean;
  float inv = 1.f / sqrtf(var + 1e-5f);
  float gv[4], bv[4], o[4];
  load4v(gamma + tid * 4, gv);
  load4v(beta + tid * 4, bv);
#pragma unroll
  for (int j = 0; j < 4; ++j) o[j] = gv[j] * (v[j] - mean) * inv + bv[j];
  store4v(Out + base, o);
}

// ---------- driver ----------
extern "C" void kernel_launch(void* const* d_in, const int* in_sizes, int n_in,
                              void* d_out, int out_size, void* d_ws, size_t ws_size,
                              hipStream_t stream)
{
  (void)in_sizes; (void)n_in; (void)out_size; (void)ws_size;
  const float* x_enc  = (const float*)d_in[0];
  const float* x_dec  = (const float*)d_in[1];
  const float* qkv_w  = (const float*)d_in[2];
  const float* qkv_b  = (const float*)d_in[3];
  const float* sa_o_w = (const float*)d_in[4];
  const float* sa_o_b = (const float*)d_in[5];
  const float* g1     = (const float*)d_in[6];
  const float* be1    = (const float*)d_in[7];
  const float* q_w    = (const float*)d_in[8];
  const float* q_b    = (const float*)d_in[9];
  const float* kv_w   = (const float*)d_in[10];
  const float* kv_b   = (const float*)d_in[11];
  const float* ca_o_w = (const float*)d_in[12];
  const float* ca_o_b = (const float*)d_in[13];
  const float* g2     = (const float*)d_in[14];
  const float* be2    = (const float*)d_in[15];
  const float* ff_w1  = (const float*)d_in[16];
  const float* ff_b1  = (const float*)d_in[17];
  const float* ff_w2  = (const float*)d_in[18];
  const float* ff_b2  = (const float*)d_in[19];
  const float* g3     = (const float*)d_in[20];
  const float* be3    = (const float*)d_in[21];
  float* out = (float*)d_out;

  u16* Wb = (u16*)d_ws;
  const size_t O_WQKV = 0;
  const size_t O_WSAO = O_WQKV + (size_t)3072 * 1024;
  const size_t O_WQ   = O_WSAO + (size_t)1024 * 1024;
  const size_t O_WKV  = O_WQ   + (size_t)1024 * 1024;
  const size_t O_WCAO = O_WKV  + (size_t)2048 * 1024;
  const size_t O_WFF1 = O_WCAO + (size_t)1024 * 1024;
  const size_t O_WFF2 = O_WFF1 + (size_t)4096 * 1024;
  const size_t O_XD   = O_WFF2 + (size_t)1024 * 4096;
  const size_t O_XE   = O_XD + 8388608;
  const size_t O_QKV  = O_XE + 8388608;              // later reused: KV_enc (+QC)
  const size_t O_QC   = O_QKV + 16777216;
  const size_t O_ATT  = O_QKV + 25165824;
  const size_t O_RES  = O_ATT + 8388608;
  const size_t O_RES2 = O_RES + 8388608;
  const size_t O_FF1  = O_RES2 + 8388608;            // pre-FFN: Vt buffers live here
  const size_t O_VT   = O_FF1;                        // Vt self [64 heads][64][2048]
  const size_t O_VT2  = O_FF1 + 8388608;              // Vt cross
  const size_t O_GO   = O_FF1 + 33554432;

  // converts
  k_cvt<<<8192, 256, 0, stream>>>(x_dec, Wb + O_XD, 2097152);
  k_cvt<<<8192, 256, 0, stream>>>(x_enc, Wb + O_XE, 2097152);
  // weight transposes (W[K][N] -> Wt[N][K] bf16)
  k_transpose_cvt<<<dim3(96, 32),  256, 0, stream>>>(qkv_w,  Wb + O_WQKV, 1024, 3072);
  k_transpose_cvt<<<dim3(32, 32),  256, 0, stream>>>(sa_o_w, Wb + O_WSAO, 1024, 1024);
  k_transpose_cvt<<<dim3(32, 32),  256, 0, stream>>>(q_w,    Wb + O_WQ,   1024, 1024);
  k_transpose_cvt<<<dim3(64, 32),  256, 0, stream>>>(kv_w,   Wb + O_WKV,  1024, 2048);
  k_transpose_cvt<<<dim3(32, 32),  256, 0, stream>>>(ca_o_w, Wb + O_WCAO, 1024, 1024);
  k_transpose_cvt<<<dim3(128, 32), 256, 0, stream>>>(ff_w1,  Wb + O_WFF1, 1024, 4096);
  k_transpose_cvt<<<dim3(32, 128), 256, 0, stream>>>(ff_w2,  Wb + O_WFF2, 4096, 1024);

  // self-attention branch
  k_gemm_bt<0><<<dim3(64, 24), 256, 0, stream>>>(Wb + O_XD, Wb + O_WQKV, qkv_b,
                                                 Wb + O_QKV, 8192, 3072, 1024);
  k_vtrans<<<dim3(32, 64), 256, 0, stream>>>(Wb + O_QKV + 128, Wb + O_VT,
                                             (long long)2048 * 3072, 192, 3072, 2048);
  k_flash2<<<dim3(32, 64), 256, 0, stream>>>(Wb + O_QKV, Wb + O_QKV + 64, Wb + O_VT,
                                             Wb + O_ATT,
                                             (long long)2048 * 3072, 192, 3072,
                                             (long long)2048 * 3072, 192, 3072,
                                             (long long)2048 * 1024, 64, 1024, 2048);
  k_gemm_bt<0><<<dim3(64, 8), 256, 0, stream>>>(Wb + O_ATT, Wb + O_WSAO, sa_o_b,
                                                Wb + O_GO, 8192, 1024, 1024);
  k_add_ln<float, u16><<<8192, 256, 0, stream>>>(Wb + O_GO, x_dec, g1, be1, Wb + O_RES);

  // cross-attention branch
  k_gemm_bt<0><<<dim3(64, 16), 256, 0, stream>>>(Wb + O_XE, Wb + O_WKV, kv_b,
                                                 Wb + O_QKV, 8192, 2048, 1024);
  k_vtrans<<<dim3(32, 64), 256, 0, stream>>>(Wb + O_QKV + 64, Wb + O_VT2,
                                             (long long)2048 * 2048, 128, 2048, 2048);
  k_gemm_bt<0><<<dim3(64, 8), 256, 0, stream>>>(Wb + O_RES, Wb + O_WQ, q_b,
                                                Wb + O_QC, 8192, 1024, 1024);
  k_flash2<<<dim3(32, 64), 256, 0, stream>>>(Wb + O_QC, Wb + O_QKV, Wb + O_VT2,
                                             Wb + O_ATT,
                                             (long long)2048 * 1024, 64, 1024,
                                             (long long)2048 * 2048, 128, 2048,
                                             (long long)2048 * 1024, 64, 1024, 2048);
  k_gemm_bt<0><<<dim3(64, 8), 256, 0, stream>>>(Wb + O_ATT, Wb + O_WCAO, ca_o_b,
                                                Wb + O_GO, 8192, 1024, 1024);
  k_add_ln<u16, u16><<<8192, 256, 0, stream>>>(Wb + O_GO, Wb + O_RES, g2, be2, Wb + O_RES2);

  // feed-forward
  k_gemm_bt<1><<<dim3(64, 32), 256, 0, stream>>>(Wb + O_RES2, Wb + O_WFF1, ff_b1,
                                                 Wb + O_FF1, 8192, 4096, 1024);
  k_gemm_bt<0><<<dim3(64, 8), 256, 0, stream>>>(Wb + O_FF1, Wb + O_WFF2, ff_b2,
                                                Wb + O_GO, 8192, 1024, 4096);
  k_add_ln<u16, float><<<8192, 256, 0, stream>>>(Wb + O_GO, Wb + O_RES2, g3, be3, out);
}

// Round 3
// 778.133 us; speedup vs baseline: 1.5286x; 1.0512x over previous
//
#include <hip/hip_runtime.h>

typedef unsigned short u16;
typedef unsigned int   u32;
typedef __bf16 bf16_t;
typedef bf16_t bf16x4 __attribute__((ext_vector_type(4)));
typedef bf16_t bf16x8 __attribute__((ext_vector_type(8)));
typedef float  f32x4  __attribute__((ext_vector_type(4)));

// ---------- fp32 <-> bf16 helpers (RNE) ----------
__device__ __forceinline__ u16 f2bf(float f) {
  u32 u = __builtin_bit_cast(u32, f);
  u32 r = u + 0x7fffu + ((u >> 16) & 1u);
  return (u16)(r >> 16);
}
__device__ __forceinline__ float bf2f(u16 h) {
  u32 u = ((u32)h) << 16;
  return __builtin_bit_cast(float, u);
}

// async global->LDS, 16B per lane. LDS dest is wave-uniform base + lane*16.
__device__ __forceinline__ void gl_lds16(const u16* g, u16* l) {
  __builtin_amdgcn_global_load_lds(
      (const __attribute__((address_space(1))) u32*)g,
      (__attribute__((address_space(3))) u32*)l, 16, 0, 0);
}

// ---------- elementwise fp32 -> bf16 convert (4 el/thread) ----------
__global__ __launch_bounds__(256) void k_cvt(const float* __restrict__ in,
                                             u16* __restrict__ out, long n4) {
  long i = (long)blockIdx.x * 256 + threadIdx.x;
  if (i >= n4) return;
  float4 v = reinterpret_cast<const float4*>(in)[i];
  ushort4 o;
  o.x = f2bf(v.x); o.y = f2bf(v.y); o.z = f2bf(v.z); o.w = f2bf(v.w);
  reinterpret_cast<ushort4*>(out)[i] = o;
}

// ---------- W[K][N] fp32 -> Wt[N][K] bf16 (32x32 tiles) ----------
__global__ __launch_bounds__(256) void k_transpose_cvt(const float* __restrict__ W,
                                                       u16* __restrict__ Wt,
                                                       int K, int N) {
  __shared__ u16 tile[32][33];
  int n0 = blockIdx.x * 32, k0 = blockIdx.y * 32;
  int tx = threadIdx.x & 31, ty = threadIdx.x >> 5;
#pragma unroll
  for (int i = 0; i < 4; ++i) {
    int k = ty + i * 8;
    tile[k][tx] = f2bf(W[(size_t)(k0 + k) * N + n0 + tx]);
  }
  __syncthreads();
#pragma unroll
  for (int i = 0; i < 4; ++i) {
    int n = ty + i * 8;
    Wt[(size_t)(n0 + n) * K + k0 + tx] = tile[tx][n];
  }
}

// ---------- bf16 V[key][64] (strided) -> Vt[64][Tk] per head ----------
__global__ __launch_bounds__(256) void k_vtrans(const u16* __restrict__ in,
                                                u16* __restrict__ out,
                                                long long ibs, int ihs, int irs,
                                                int Tk) {
  __shared__ u16 t[64][72];
  const int tid = threadIdx.x;
  const int head = blockIdx.y;
  const int b = head >> 4, h = head & 15;
  const int kt = blockIdx.x * 64;
  const u16* ip = in + (size_t)b * ibs + (size_t)h * ihs;
  u16* op = out + (size_t)head * 64 * Tk;
#pragma unroll
  for (int i = 0; i < 2; ++i) {
    int c = i * 256 + tid;
    int key = c >> 3, d = (c & 7) * 8;
    *reinterpret_cast<uint4*>(&t[key][d]) =
        *reinterpret_cast<const uint4*>(ip + (size_t)(kt + key) * irs + d);
  }
  __syncthreads();
#pragma unroll
  for (int i = 0; i < 2; ++i) {
    int c = i * 256 + tid;
    int d = c >> 3, k8 = (c & 7) * 8;
    ushort4 lo, hi;
    lo.x = t[k8 + 0][d]; lo.y = t[k8 + 1][d]; lo.z = t[k8 + 2][d]; lo.w = t[k8 + 3][d];
    hi.x = t[k8 + 4][d]; hi.y = t[k8 + 5][d]; hi.z = t[k8 + 6][d]; hi.w = t[k8 + 7][d];
    uint4 o;
    o.x = ((u32)lo.y << 16) | lo.x; o.y = ((u32)lo.w << 16) | lo.z;
    o.z = ((u32)hi.y << 16) | hi.x; o.w = ((u32)hi.w << 16) | hi.z;
    *reinterpret_cast<uint4*>(op + (size_t)d * Tk + kt + k8) = o;
  }
}

// ---------- GEMM (m97 structure): C = A @ Bt^T + bias, global_load_lds ----------
template<int RELU>
__global__ __launch_bounds__(256) void k_gemm_bt(
    const u16* __restrict__ A, const u16* __restrict__ Bt,
    const float* __restrict__ bias, u16* __restrict__ C,
    int M, int N, int K)
{
  __shared__ __align__(16) u16 As[128 * 64];   // linear [row][64]
  __shared__ __align__(16) u16 Bs[128 * 64];
  const int tid = threadIdx.x;
  const int lane = tid & 63, wid = tid >> 6;
  const int wr = wid >> 1, wc = wid & 1;
  const int l15 = lane & 15, g = lane >> 4;
  const int bm = blockIdx.x * 128, bn = blockIdx.y * 128;
  const int srow = lane >> 3, scol = (lane & 7) * 8;

  f32x4 acc[4][4] = {};

  for (int kt = 0; kt < K; kt += 64) {
#pragma unroll
    for (int i = 0; i < 4; ++i) {
      int ch = wid * 4 + i;                     // chunk: 8 rows of 64
      gl_lds16(A  + (size_t)(bm + ch * 8 + srow) * K + kt + scol, &As[ch * 512]);
      gl_lds16(Bt + (size_t)(bn + ch * 8 + srow) * K + kt + scol, &Bs[ch * 512]);
    }
    __syncthreads();
#pragma unroll
    for (int ks = 0; ks < 2; ++ks) {
      bf16x8 af[4], bfr[4];
#pragma unroll
      for (int m = 0; m < 4; ++m)
        af[m] = *reinterpret_cast<const bf16x8*>(&As[(wr * 64 + m * 16 + l15) * 64 + ks * 32 + g * 8]);
#pragma unroll
      for (int n = 0; n < 4; ++n)
        bfr[n] = *reinterpret_cast<const bf16x8*>(&Bs[(wc * 64 + n * 16 + l15) * 64 + ks * 32 + g * 8]);
      __builtin_amdgcn_s_setprio(1);
#pragma unroll
      for (int m = 0; m < 4; ++m)
#pragma unroll
        for (int n = 0; n < 4; ++n)
          acc[m][n] = __builtin_amdgcn_mfma_f32_16x16x32_bf16(af[m], bfr[n], acc[m][n], 0, 0, 0);
      __builtin_amdgcn_s_setprio(0);
    }
    __syncthreads();
  }
#pragma unroll
  for (int n = 0; n < 4; ++n) {
    int col = bn + wc * 64 + n * 16 + l15;
    float bv = bias[col];
#pragma unroll
    for (int m = 0; m < 4; ++m) {
      int row0 = bm + wr * 64 + m * 16 + g * 4;
#pragma unroll
      for (int r = 0; r < 4; ++r) {
        float v = acc[m][n][r] + bv;
        if (RELU) v = fmaxf(v, 0.f);
        C[(size_t)(row0 + r) * N + col] = f2bf(v);
      }
    }
  }
}

// ---------- flash attention v3: swapped QK^T, T14 async-stage, exp2 softmax ----------
__global__ __launch_bounds__(256) void k_flash2(
    const u16* __restrict__ Qg, const u16* __restrict__ Kg, const u16* __restrict__ VTg,
    u16* __restrict__ Og,
    long long qbs, int qhs, int qrs,
    long long kbs, int khs, int krs,
    long long obs, int ohs, int ors,
    int Tk)
{
  __shared__ __align__(16) u16 Ks[64][72];
  __shared__ __align__(16) u16 Vs[64][72];     // Vs[d][key]
  __shared__ __align__(16) u16 Ps[4][16][72];  // per-wave P tile [qrow][key]
  const int tid = threadIdx.x;
  const int lane = tid & 63, wid = tid >> 6;
  const int l15 = lane & 15, g = lane >> 4;
  const int head = blockIdx.y;
  const int b = head >> 4, h = head & 15;
  const int srow = tid >> 3, scol = (tid & 7) * 8;   // staging coords

  const u16* Q  = Qg + (size_t)b * qbs + (size_t)h * qhs;
  const u16* Kp = Kg + (size_t)b * kbs + (size_t)h * khs;
  const u16* Vp = VTg + (size_t)head * 64 * Tk;
  u16* Op = Og + (size_t)b * obs + (size_t)h * ohs;

  const int q0 = blockIdx.x * 64 + wid * 16;
  const float SCL = 0.125f * 1.44269504f;   // base-2 domain scale

  bf16x8 qf[2];
#pragma unroll
  for (int ks = 0; ks < 2; ++ks)
    qf[ks] = *reinterpret_cast<const bf16x8*>(Q + (size_t)(q0 + l15) * qrs + ks * 32 + g * 8);

  f32x4 oacc[4] = {};
  float mt = -1e30f, l = 0.f;   // base-2-domain stats for q-row l15

  uint4 ka0, ka1, va0, va1, kb0, kb1, vb0, vb1;

  auto load_set = [&](int kt, uint4& k0, uint4& k1, uint4& v0, uint4& v1) {
    k0 = *reinterpret_cast<const uint4*>(Kp + (size_t)(kt + srow) * krs + scol);
    k1 = *reinterpret_cast<const uint4*>(Kp + (size_t)(kt + srow + 32) * krs + scol);
    v0 = *reinterpret_cast<const uint4*>(Vp + (size_t)srow * Tk + kt + scol);
    v1 = *reinterpret_cast<const uint4*>(Vp + (size_t)(srow + 32) * Tk + kt + scol);
  };

  auto tile = [&](const uint4& k0, const uint4& k1, const uint4& v0, const uint4& v1,
                  int ktn, uint4& nk0, uint4& nk1, uint4& nv0, uint4& nv1) {
    __syncthreads();   // previous compute done reading LDS
    *reinterpret_cast<uint4*>(&Ks[srow][scol])      = k0;
    *reinterpret_cast<uint4*>(&Ks[srow + 32][scol]) = k1;
    *reinterpret_cast<uint4*>(&Vs[srow][scol])      = v0;
    *reinterpret_cast<uint4*>(&Vs[srow + 32][scol]) = v1;
    // T14: issue next tile's loads now; latency hides under compute below
    load_set(ktn, nk0, nk1, nv0, nv1);
    __syncthreads();   // staging visible

    f32x4 sc[4] = {};
    __builtin_amdgcn_s_setprio(1);
#pragma unroll
    for (int ks = 0; ks < 2; ++ks)
#pragma unroll
      for (int kb = 0; kb < 4; ++kb) {
        bf16x8 kf = *reinterpret_cast<const bf16x8*>(&Ks[kb * 16 + l15][ks * 32 + g * 8]);
        sc[kb] = __builtin_amdgcn_mfma_f32_16x16x32_bf16(kf, qf[ks], sc[kb], 0, 0, 0);
      }
    __builtin_amdgcn_s_setprio(0);

    // row max in raw domain (16 local + 2 shuffles)
    float pm = -1e30f;
#pragma unroll
    for (int kb = 0; kb < 4; ++kb)
#pragma unroll
      for (int r = 0; r < 4; ++r) pm = fmaxf(pm, sc[kb][r]);
    pm = fmaxf(pm, __shfl_xor(pm, 16));
    pm = fmaxf(pm, __shfl_xor(pm, 32));
    float tm = pm * SCL;

    const bool rescale = !__all(tm <= mt + 8.f);   // defer-max (T13), base-2
    float scl = 1.f;
    if (rescale) {
      float mnew = fmaxf(mt, tm);
      scl = __builtin_amdgcn_exp2f(mt - mnew);
      mt = mnew;
    }
    float ls = 0.f;
#pragma unroll
    for (int kb = 0; kb < 4; ++kb) {
      bf16x4 pk;
#pragma unroll
      for (int r = 0; r < 4; ++r) {
        float e = __builtin_amdgcn_exp2f(__builtin_fmaf(sc[kb][r], SCL, -mt));
        ls += e;
        pk[r] = (bf16_t)e;
      }
      *reinterpret_cast<bf16x4*>(&Ps[wid][l15][kb * 16 + g * 4]) = pk;
    }
    ls += __shfl_xor(ls, 16);
    ls += __shfl_xor(ls, 32);
    if (rescale) {
      l = l * scl + ls;
#pragma unroll
      for (int r = 0; r < 4; ++r) {
        float sr = __shfl(scl, 20 * g + r);
#pragma unroll
        for (int nb = 0; nb < 4; ++nb) oacc[nb][r] *= sr;
      }
    } else {
      l += ls;
    }
    asm volatile("s_waitcnt lgkmcnt(0)" ::: "memory");
#pragma unroll
    for (int kc = 0; kc < 2; ++kc) {
      bf16x8 pf = *reinterpret_cast<const bf16x8*>(&Ps[wid][l15][kc * 32 + g * 8]);
      __builtin_amdgcn_s_setprio(1);
#pragma unroll
      for (int nb = 0; nb < 4; ++nb) {
        bf16x8 vf = *reinterpret_cast<const bf16x8*>(&Vs[nb * 16 + l15][kc * 32 + g * 8]);
        oacc[nb] = __builtin_amdgcn_mfma_f32_16x16x32_bf16(pf, vf, oacc[nb], 0, 0, 0);
      }
      __builtin_amdgcn_s_setprio(0);
    }
  };

  load_set(0, ka0, ka1, va0, va1);
  for (int kt = 0; kt < Tk; kt += 128) {
    tile(ka0, ka1, va0, va1, kt + 64, kb0, kb1, vb0, vb1);
    int ktn = (kt + 128 < Tk) ? kt + 128 : 0;   // last prefetch harmless
    tile(kb0, kb1, vb0, vb1, ktn, ka0, ka1, va0, va1);
  }

#pragma unroll
  for (int r = 0; r < 4; ++r) {
    float lr = __shfl(l, 20 * g + r);
    float inv = 1.f / lr;
#pragma unroll
    for (int nb = 0; nb < 4; ++nb)
      Op[(size_t)(q0 + g * 4 + r) * ors + nb * 16 + l15] = f2bf(oacc[nb][r] * inv);
  }
}

// ---------- fused add + LayerNorm over D=1024 (one row per block) ----------
__device__ __forceinline__ void load4v(const float* p, float* v) {
  float4 t = *reinterpret_cast<const float4*>(p);
  v[0] = t.x; v[1] = t.y; v[2] = t.z; v[3] = t.w;
}
__device__ __forceinline__ void load4v(const u16* p, float* v) {
  ushort4 t = *reinterpret_cast<const ushort4*>(p);
  v[0] = bf2f(t.x); v[1] = bf2f(t.y); v[2] = bf2f(t.z); v[3] = bf2f(t.w);
}
__device__ __forceinline__ void store4v(float* p, const float* v) {
  float4 t; t.x = v[0]; t.y = v[1]; t.z = v[2]; t.w = v[3];
  *reinterpret_cast<float4*>(p) = t;
}
__device__ __forceinline__ void store4v(u16* p, const float* v) {
  ushort4 t; t.x = f2bf(v[0]); t.y = f2bf(v[1]); t.z = f2bf(v[2]); t.w = f2bf(v[3]);
  *reinterpret_cast<ushort4*>(p) = t;
}

template<typename TRES, typename TOUT>
__global__ __launch_bounds__(256) void k_add_ln(
    const u16* __restrict__ X, const TRES* __restrict__ R,
    const float* __restrict__ gamma, const float* __restrict__ beta,
    TOUT* __restrict__ Out)
{
  const int row = blockIdx.x;
  const int tid = threadIdx.x;
  const size_t base = (size_t)row * 1024 + tid * 4;
  float x[4], rr[4];
  load4v(X + base, x);
  load4v(R + base, rr);
  float v[4];
#pragma unroll
  for (int j = 0; j < 4; ++j) v[j] = x[j] + rr[j];
  float s = v[0] + v[1] + v[2] + v[3];
  float q = v[0]*v[0] + v[1]*v[1] + v[2]*v[2] + v[3]*v[3];
#pragma unroll
  for (int off = 32; off > 0; off >>= 1) {
    s += __shfl_down(s, off);
    q += __shfl_down(q, off);
  }
  __shared__ float sh[8];
  const int lane = tid & 63, wid = tid >> 6;
  if (lane == 0) { sh[wid] = s; sh[4 + wid] = q; }
  __syncthreads();
  s = sh[0] + sh[1] + sh[2] + sh[3];
  q = sh[4] + sh[5] + sh[6] + sh[7];
  float mean = s * (1.f / 1024.f);
  float var = q * (1.f / 1024.f) - mean * mean;
  float inv = 1.f / sqrtf(var + 1e-5f);
  float gv[4], bv[4], o[4];
  load4v(gamma + tid * 4, gv);
  load4v(beta + tid * 4, bv);
#pragma unroll
  for (int j = 0; j < 4; ++j) o[j] = gv[j] * (v[j] - mean) * inv + bv[j];
  store4v(Out + base, o);
}

// ---------- driver ----------
extern "C" void kernel_launch(void* const* d_in, const int* in_sizes, int n_in,
                              void* d_out, int out_size, void* d_ws, size_t ws_size,
                              hipStream_t stream)
{
  (void)in_sizes; (void)n_in; (void)out_size; (void)ws_size;
  const float* x_enc  = (const float*)d_in[0];
  const float* x_dec  = (const float*)d_in[1];
  const float* qkv_w  = (const float*)d_in[2];
  const float* qkv_b  = (const float*)d_in[3];
  const float* sa_o_w = (const float*)d_in[4];
  const float* sa_o_b = (const float*)d_in[5];
  const float* g1     = (const float*)d_in[6];
  const float* be1    = (const float*)d_in[7];
  const float* q_w    = (const float*)d_in[8];
  const float* q_b    = (const float*)d_in[9];
  const float* kv_w   = (const float*)d_in[10];
  const float* kv_b   = (const float*)d_in[11];
  const float* ca_o_w = (const float*)d_in[12];
  const float* ca_o_b = (const float*)d_in[13];
  const float* g2     = (const float*)d_in[14];
  const float* be2    = (const float*)d_in[15];
  const float* ff_w1  = (const float*)d_in[16];
  const float* ff_b1  = (const float*)d_in[17];
  const float* ff_w2  = (const float*)d_in[18];
  const float* ff_b2  = (const float*)d_in[19];
  const float* g3     = (const float*)d_in[20];
  const float* be3    = (const float*)d_in[21];
  float* out = (float*)d_out;

  u16* Wb = (u16*)d_ws;
  const size_t O_WQKV = 0;
  const size_t O_WSAO = O_WQKV + (size_t)3072 * 1024;
  const size_t O_WQ   = O_WSAO + (size_t)1024 * 1024;
  const size_t O_WKV  = O_WQ   + (size_t)1024 * 1024;
  const size_t O_WCAO = O_WKV  + (size_t)2048 * 1024;
  const size_t O_WFF1 = O_WCAO + (size_t)1024 * 1024;
  const size_t O_WFF2 = O_WFF1 + (size_t)4096 * 1024;
  const size_t O_XD   = O_WFF2 + (size_t)1024 * 4096;
  const size_t O_XE   = O_XD + 8388608;
  const size_t O_QKV  = O_XE + 8388608;
  const size_t O_QC   = O_QKV + 16777216;
  const size_t O_ATT  = O_QKV + 25165824;
  const size_t O_RES  = O_ATT + 8388608;
  const size_t O_RES2 = O_RES + 8388608;
  const size_t O_FF1  = O_RES2 + 8388608;
  const size_t O_VT   = O_FF1;
  const size_t O_VT2  = O_FF1 + 8388608;
  const size_t O_GO   = O_FF1 + 33554432;

  k_cvt<<<8192, 256, 0, stream>>>(x_dec, Wb + O_XD, 2097152);
  k_cvt<<<8192, 256, 0, stream>>>(x_enc, Wb + O_XE, 2097152);
  k_transpose_cvt<<<dim3(96, 32),  256, 0, stream>>>(qkv_w,  Wb + O_WQKV, 1024, 3072);
  k_transpose_cvt<<<dim3(32, 32),  256, 0, stream>>>(sa_o_w, Wb + O_WSAO, 1024, 1024);
  k_transpose_cvt<<<dim3(32, 32),  256, 0, stream>>>(q_w,    Wb + O_WQ,   1024, 1024);
  k_transpose_cvt<<<dim3(64, 32),  256, 0, stream>>>(kv_w,   Wb + O_WKV,  1024, 2048);
  k_transpose_cvt<<<dim3(32, 32),  256, 0, stream>>>(ca_o_w, Wb + O_WCAO, 1024, 1024);
  k_transpose_cvt<<<dim3(128, 32), 256, 0, stream>>>(ff_w1,  Wb + O_WFF1, 1024, 4096);
  k_transpose_cvt<<<dim3(32, 128), 256, 0, stream>>>(ff_w2,  Wb + O_WFF2, 4096, 1024);

  // self-attention branch
  k_gemm_bt<0><<<dim3(64, 24), 256, 0, stream>>>(Wb + O_XD, Wb + O_WQKV, qkv_b,
                                                 Wb + O_QKV, 8192, 3072, 1024);
  k_vtrans<<<dim3(32, 64), 256, 0, stream>>>(Wb + O_QKV + 128, Wb + O_VT,
                                             (long long)2048 * 3072, 192, 3072, 2048);
  k_flash2<<<dim3(32, 64), 256, 0, stream>>>(Wb + O_QKV, Wb + O_QKV + 64, Wb + O_VT,
                                             Wb + O_ATT,
                                             (long long)2048 * 3072, 192, 3072,
                                             (long long)2048 * 3072, 192, 3072,
                                             (long long)2048 * 1024, 64, 1024, 2048);
  k_gemm_bt<0><<<dim3(64, 8), 256, 0, stream>>>(Wb + O_ATT, Wb + O_WSAO, sa_o_b,
                                                Wb + O_GO, 8192, 1024, 1024);
  k_add_ln<float, u16><<<8192, 256, 0, stream>>>(Wb + O_GO, x_dec, g1, be1, Wb + O_RES);

  // cross-attention branch
  k_gemm_bt<0><<<dim3(64, 16), 256, 0, stream>>>(Wb + O_XE, Wb + O_WKV, kv_b,
                                                 Wb + O_QKV, 8192, 2048, 1024);
  k_vtrans<<<dim3(32, 64), 256, 0, stream>>>(Wb + O_QKV + 64, Wb + O_VT2,
                                             (long long)2048 * 2048, 128, 2048, 2048);
  k_gemm_bt<0><<<dim3(64, 8), 256, 0, stream>>>(Wb + O_RES, Wb + O_WQ, q_b,
                                                Wb + O_QC, 8192, 1024, 1024);
  k_flash2<<<dim3(32, 64), 256, 0, stream>>>(Wb + O_QC, Wb + O_QKV, Wb + O_VT2,
                                             Wb + O_ATT,
                                             (long long)2048 * 1024, 64, 1024,
                                             (long long)2048 * 2048, 128, 2048,
                                             (long long)2048 * 1024, 64, 1024, 2048);
  k_gemm_bt<0><<<dim3(64, 8), 256, 0, stream>>>(Wb + O_ATT, Wb + O_WCAO, ca_o_b,
                                                Wb + O_GO, 8192, 1024, 1024);
  k_add_ln<u16, u16><<<8192, 256, 0, stream>>>(Wb + O_GO, Wb + O_RES, g2, be2, Wb + O_RES2);

  // feed-forward
  k_gemm_bt<1><<<dim3(64, 32), 256, 0, stream>>>(Wb + O_RES2, Wb + O_WFF1, ff_b1,
                                                 Wb + O_FF1, 8192, 4096, 1024);
  k_gemm_bt<0><<<dim3(64, 8), 256, 0, stream>>>(Wb + O_FF1, Wb + O_WFF2, ff_b2,
                                                Wb + O_GO, 8192, 1024, 4096);
  k_add_ln<u16, float><<<8192, 256, 0, stream>>>(Wb + O_GO, Wb + O_RES2, g3, be3, out);
}